// Round 1
// baseline (471.368 us; speedup 1.0000x reference)
//
#include <hip/hip_runtime.h>

// ---------------------------------------------------------------------------
// 2-layer GCN: out = relu(GCN(relu(GCN(x,W1,b1)), W2, b2))
// GCN(v) = dinv[v] * ( sum_{u->v} g[u] + g[v] ) + b,  g[u] = (in @ W)[u] * dinv[u]
// dinv[v] = rsqrt(indeg(v) + 1)   (self-loop)
// Strategy: build CSR by dst once per call (scan + atomic cursor), then
// gather-aggregate (1 wave per node, lanes = feature chunks) -> no float atomics.
// ---------------------------------------------------------------------------

__global__ void init_deg_kernel(int* __restrict__ deg, int n) {
    int i = blockIdx.x * blockDim.x + threadIdx.x;
    if (i < n) deg[i] = 0;
}

__global__ void count_deg_kernel(const int* __restrict__ dst, int* __restrict__ deg, int E) {
    int e = blockIdx.x * blockDim.x + threadIdx.x;
    if (e < E) atomicAdd(&deg[dst[e]], 1);
}

__global__ void dinv_kernel(const int* __restrict__ deg, float* __restrict__ dinv, int n) {
    int i = blockIdx.x * blockDim.x + threadIdx.x;
    if (i < n) dinv[i] = rsqrtf((float)(deg[i] + 1));
}

// ---- 3-kernel exclusive scan of deg -> rowstart (and cursor copy) ----------
__global__ void partial_sum_kernel(const int* __restrict__ deg, int* __restrict__ partial, int n) {
    __shared__ int sd[256];
    int t = threadIdx.x;
    int i = blockIdx.x * 256 + t;
    sd[t] = (i < n) ? deg[i] : 0;
    __syncthreads();
    for (int off = 128; off > 0; off >>= 1) {
        if (t < off) sd[t] += sd[t + off];
        __syncthreads();
    }
    if (t == 0) partial[blockIdx.x] = sd[0];
}

__global__ void scan_partials_kernel(int* __restrict__ partial, int nb) {
    __shared__ int sd[256];
    int t = threadIdx.x;
    int v = (t < nb) ? partial[t] : 0;
    sd[t] = v;
    __syncthreads();
    for (int off = 1; off < 256; off <<= 1) {
        int x = (t >= off) ? sd[t - off] : 0;
        __syncthreads();
        sd[t] += x;
        __syncthreads();
    }
    if (t < nb) partial[t] = sd[t] - v;  // exclusive
}

__global__ void scan_final_kernel(const int* __restrict__ deg, const int* __restrict__ partial,
                                  int* __restrict__ rowstart, int* __restrict__ cursor,
                                  int n, int E) {
    __shared__ int sd[256];
    int t = threadIdx.x;
    int b = blockIdx.x;
    int i = b * 256 + t;
    int v = (i < n) ? deg[i] : 0;
    sd[t] = v;
    __syncthreads();
    for (int off = 1; off < 256; off <<= 1) {
        int x = (t >= off) ? sd[t - off] : 0;
        __syncthreads();
        sd[t] += x;
        __syncthreads();
    }
    int excl = partial[b] + sd[t] - v;
    if (i < n) { rowstart[i] = excl; cursor[i] = excl; }
    if (i == 0) rowstart[n] = E;
}

__global__ void fill_csr_kernel(const int* __restrict__ src, const int* __restrict__ dst,
                                int* __restrict__ cursor, int* __restrict__ csr, int E) {
    int e = blockIdx.x * blockDim.x + threadIdx.x;
    if (e < E) {
        int d = dst[e];
        int pos = atomicAdd(&cursor[d], 1);
        csr[pos] = src[e];
    }
}

// ---- fp32 GEMM: out[r][c] = dinv[r] * sum_k A[r][k]*W[k][c]  (K=128 fixed) ---
// BM=64, BN=128, BK=64, block=256 threads, 4x8 register tile.
// xsT stored k-major, pad 68 -> aligned b128 reads, conflict-free.
__global__ __launch_bounds__(256) void gemm_kernel(const float* __restrict__ A,
                                                   const float* __restrict__ W,
                                                   const float* __restrict__ dinv,
                                                   float* __restrict__ out,
                                                   int n, int nout) {
    __shared__ float xsT[64][68];   // [k][row]
    __shared__ float ws[64][128];   // [k][col]
    int t = threadIdx.x;
    int row0 = blockIdx.x * 64;
    int col0 = blockIdx.y * 128;
    int tc = t & 15, tr = t >> 4;

    float acc[4][8];
#pragma unroll
    for (int ri = 0; ri < 4; ri++)
#pragma unroll
        for (int ci = 0; ci < 8; ci++) acc[ri][ci] = 0.f;

    for (int kt = 0; kt < 128; kt += 64) {
        // stage W tile (64x128 floats)
#pragma unroll
        for (int i = 0; i < 8; i++) {
            int flat = i * 1024 + t * 4;
            int k = flat >> 7, c = flat & 127;
            *(float4*)&ws[k][c] = *(const float4*)&W[(size_t)(kt + k) * nout + col0 + c];
        }
        // stage x tile transposed (64 rows x 64 k)
#pragma unroll
        for (int i = 0; i < 4; i++) {
            int flat = i * 1024 + t * 4;
            int r = flat >> 6, kk = flat & 63;
            int row = row0 + r;
            float4 xv = make_float4(0.f, 0.f, 0.f, 0.f);
            if (row < n) xv = *(const float4*)&A[(size_t)row * 128 + kt + kk];
            xsT[kk + 0][r] = xv.x;
            xsT[kk + 1][r] = xv.y;
            xsT[kk + 2][r] = xv.z;
            xsT[kk + 3][r] = xv.w;
        }
        __syncthreads();
#pragma unroll 8
        for (int k = 0; k < 64; k++) {
            float4 av = *(float4*)&xsT[k][tr * 4];
            float4 b0 = *(float4*)&ws[k][tc * 8];
            float4 b1 = *(float4*)&ws[k][tc * 8 + 4];
            float a[4] = {av.x, av.y, av.z, av.w};
            float bb[8] = {b0.x, b0.y, b0.z, b0.w, b1.x, b1.y, b1.z, b1.w};
#pragma unroll
            for (int ri = 0; ri < 4; ri++)
#pragma unroll
                for (int ci = 0; ci < 8; ci++)
                    acc[ri][ci] = fmaf(a[ri], bb[ci], acc[ri][ci]);
        }
        __syncthreads();
    }

#pragma unroll
    for (int ri = 0; ri < 4; ri++) {
        int row = row0 + tr * 4 + ri;
        if (row < n) {
            float dv = dinv[row];
            float4 o0 = make_float4(acc[ri][0] * dv, acc[ri][1] * dv, acc[ri][2] * dv, acc[ri][3] * dv);
            float4 o1 = make_float4(acc[ri][4] * dv, acc[ri][5] * dv, acc[ri][6] * dv, acc[ri][7] * dv);
            float* po = out + (size_t)row * nout + col0 + tc * 8;
            *(float4*)po = o0;
            *(float4*)(po + 4) = o1;
        }
    }
}

// ---- gather aggregation: out[v] = relu(dinv[v]*(g[v] + sum_{u->v} g[u]) + b)
// one wave per node; lane holds VEC contiguous features. VEC=2 -> F=128, VEC=4 -> F=256.
template <int VEC>
__global__ __launch_bounds__(256) void agg_kernel(const float* __restrict__ g,
                                                  const int* __restrict__ rowstart,
                                                  const int* __restrict__ csr,
                                                  const float* __restrict__ dinv,
                                                  const float* __restrict__ bias,
                                                  float* __restrict__ out, int n) {
    int wid = (blockIdx.x * blockDim.x + threadIdx.x) >> 6;
    int lane = threadIdx.x & 63;
    if (wid >= n) return;
    const int F = 64 * VEC;
    int beg = rowstart[wid];
    int end = rowstart[wid + 1];

    float acc[VEC];
    {   // self term
        const float* p = g + (size_t)wid * F + lane * VEC;
        if (VEC == 4) {
            float4 v = *(const float4*)p;
            acc[0] = v.x; acc[1] = v.y; acc[2] = v.z; acc[3] = v.w;
        } else {
            float2 v = *(const float2*)p;
            acc[0] = v.x; acc[1] = v.y;
        }
    }
    for (int e = beg; e < end; ++e) {
        int u = csr[e];
        const float* p = g + (size_t)u * F + lane * VEC;
        if (VEC == 4) {
            float4 v = *(const float4*)p;
            acc[0] += v.x; acc[1] += v.y; acc[2] += v.z; acc[3] += v.w;
        } else {
            float2 v = *(const float2*)p;
            acc[0] += v.x; acc[1] += v.y;
        }
    }
    float dv = dinv[wid];
    float* po = out + (size_t)wid * F + lane * VEC;
    if (VEC == 4) {
        float4 o;
        o.x = fmaxf(fmaf(acc[0], dv, bias[lane * 4 + 0]), 0.f);
        o.y = fmaxf(fmaf(acc[1], dv, bias[lane * 4 + 1]), 0.f);
        o.z = fmaxf(fmaf(acc[2], dv, bias[lane * 4 + 2]), 0.f);
        o.w = fmaxf(fmaf(acc[3], dv, bias[lane * 4 + 3]), 0.f);
        *(float4*)po = o;
    } else {
        float2 o;
        o.x = fmaxf(fmaf(acc[0], dv, bias[lane * 2 + 0]), 0.f);
        o.y = fmaxf(fmaf(acc[1], dv, bias[lane * 2 + 1]), 0.f);
        *(float2*)po = o;
    }
}

extern "C" void kernel_launch(void* const* d_in, const int* in_sizes, int n_in,
                              void* d_out, int out_size, void* d_ws, size_t ws_size,
                              hipStream_t stream) {
    const float* x  = (const float*)d_in[0];
    const int*   ei = (const int*)d_in[1];
    const float* W1 = (const float*)d_in[2];
    const float* b1 = (const float*)d_in[3];
    const float* W2 = (const float*)d_in[4];
    const float* b2 = (const float*)d_in[5];
    float* out = (float*)d_out;

    int N = in_sizes[0] / 128;   // 50000
    int E = in_sizes[1] / 2;     // 800000
    const int* src = ei;
    const int* dst = ei + E;

    // workspace carve-up (256B aligned regions)
    char* w = (char*)d_ws;
    size_t off = 0;
    auto alloc = [&](size_t bytes) -> char* {
        char* p = w + off;
        off = (off + bytes + 255) & ~(size_t)255;
        return p;
    };
    int*   deg      = (int*)alloc((size_t)N * 4);
    int*   rowstart = (int*)alloc((size_t)(N + 1) * 4);
    int*   cursor   = (int*)alloc((size_t)N * 4);
    int*   partial  = (int*)alloc(256 * 4);
    float* dinv     = (float*)alloc((size_t)N * 4);
    int*   csr      = (int*)alloc((size_t)E * 4);
    float* o1       = (float*)alloc((size_t)N * 128 * 4);
    float* gbuf     = (float*)alloc((size_t)N * 256 * 4);

    int nb_n = (N + 255) / 256;   // 196
    int nb_e = (E + 255) / 256;

    hipLaunchKernelGGL(init_deg_kernel,     dim3(nb_n), dim3(256), 0, stream, deg, N);
    hipLaunchKernelGGL(count_deg_kernel,    dim3(nb_e), dim3(256), 0, stream, dst, deg, E);
    hipLaunchKernelGGL(dinv_kernel,         dim3(nb_n), dim3(256), 0, stream, deg, dinv, N);
    hipLaunchKernelGGL(partial_sum_kernel,  dim3(nb_n), dim3(256), 0, stream, deg, partial, N);
    hipLaunchKernelGGL(scan_partials_kernel,dim3(1),    dim3(256), 0, stream, partial, nb_n);
    hipLaunchKernelGGL(scan_final_kernel,   dim3(nb_n), dim3(256), 0, stream, deg, partial, rowstart, cursor, N, E);
    hipLaunchKernelGGL(fill_csr_kernel,     dim3(nb_e), dim3(256), 0, stream, src, dst, cursor, csr, E);

    // layer 1: g1 = (x@W1)*dinv ; o1 = relu(dinv*(agg g1) + b1)
    hipLaunchKernelGGL(gemm_kernel, dim3((N + 63) / 64, 1), dim3(256), 0, stream, x, W1, dinv, gbuf, N, 128);
    hipLaunchKernelGGL(agg_kernel<2>, dim3((N + 3) / 4), dim3(256), 0, stream, gbuf, rowstart, csr, dinv, b1, o1, N);

    // layer 2: g2 = (o1@W2)*dinv ; out = relu(dinv*(agg g2) + b2)
    hipLaunchKernelGGL(gemm_kernel, dim3((N + 63) / 64, 2), dim3(256), 0, stream, o1, W2, dinv, gbuf, N, 256);
    hipLaunchKernelGGL(agg_kernel<4>, dim3((N + 3) / 4), dim3(256), 0, stream, gbuf, rowstart, csr, dinv, b2, out, N);
}

// Round 2
// 333.333 us; speedup vs baseline: 1.4141x; 1.4141x over previous
//
#include <hip/hip_runtime.h>

// ---------------------------------------------------------------------------
// 2-layer GCN: out = relu(GCN(relu(GCN(x,W1,b1)), W2, b2))
// GCN(v) = dinv[v] * ( sum_{u->v} g[u] + g[v] ) + b,  g[u] = (in @ W)[u] * dinv[u]
// R2: fp16 everywhere in the middle. MFMA fp16 GEMM (fp32 acc), g stored fp16
// to halve the gather traffic (the R1 bottleneck: 398 MB FETCH @ 3.76 TB/s).
// ---------------------------------------------------------------------------

typedef __attribute__((ext_vector_type(8))) _Float16 half8;
typedef __attribute__((ext_vector_type(4))) _Float16 half4v;
typedef __attribute__((ext_vector_type(2))) _Float16 half2v;
typedef __attribute__((ext_vector_type(4))) float floatx4;

__global__ void init_deg_kernel(int* __restrict__ deg, int n) {
    int i = blockIdx.x * blockDim.x + threadIdx.x;
    if (i < n) deg[i] = 0;
}

__global__ void count_deg_kernel(const int* __restrict__ dst, int* __restrict__ deg, int E) {
    int e = blockIdx.x * blockDim.x + threadIdx.x;
    if (e < E) atomicAdd(&deg[dst[e]], 1);
}

__global__ void dinv_kernel(const int* __restrict__ deg, float* __restrict__ dinv, int n) {
    int i = blockIdx.x * blockDim.x + threadIdx.x;
    if (i < n) dinv[i] = rsqrtf((float)(deg[i] + 1));
}

// ---- 3-kernel exclusive scan of deg -> rowstart (and cursor copy) ----------
__global__ void partial_sum_kernel(const int* __restrict__ deg, int* __restrict__ partial, int n) {
    __shared__ int sd[256];
    int t = threadIdx.x;
    int i = blockIdx.x * 256 + t;
    sd[t] = (i < n) ? deg[i] : 0;
    __syncthreads();
    for (int off = 128; off > 0; off >>= 1) {
        if (t < off) sd[t] += sd[t + off];
        __syncthreads();
    }
    if (t == 0) partial[blockIdx.x] = sd[0];
}

__global__ void scan_partials_kernel(int* __restrict__ partial, int nb) {
    __shared__ int sd[256];
    int t = threadIdx.x;
    int v = (t < nb) ? partial[t] : 0;
    sd[t] = v;
    __syncthreads();
    for (int off = 1; off < 256; off <<= 1) {
        int x = (t >= off) ? sd[t - off] : 0;
        __syncthreads();
        sd[t] += x;
        __syncthreads();
    }
    if (t < nb) partial[t] = sd[t] - v;  // exclusive
}

__global__ void scan_final_kernel(const int* __restrict__ deg, const int* __restrict__ partial,
                                  int* __restrict__ rowstart, int* __restrict__ cursor,
                                  int n, int E) {
    __shared__ int sd[256];
    int t = threadIdx.x;
    int b = blockIdx.x;
    int i = b * 256 + t;
    int v = (i < n) ? deg[i] : 0;
    sd[t] = v;
    __syncthreads();
    for (int off = 1; off < 256; off <<= 1) {
        int x = (t >= off) ? sd[t - off] : 0;
        __syncthreads();
        sd[t] += x;
        __syncthreads();
    }
    int excl = partial[b] + sd[t] - v;
    if (i < n) { rowstart[i] = excl; cursor[i] = excl; }
    if (i == 0) rowstart[n] = E;
}

__global__ void fill_csr_kernel(const int* __restrict__ src, const int* __restrict__ dst,
                                int* __restrict__ cursor, int* __restrict__ csr, int E) {
    int e = blockIdx.x * blockDim.x + threadIdx.x;
    if (e < E) {
        int d = dst[e];
        int pos = atomicAdd(&cursor[d], 1);
        csr[pos] = src[e];
    }
}

// ---- converts ---------------------------------------------------------------
__global__ void conv_x_kernel(const float* __restrict__ x, _Float16* __restrict__ xh, int total4) {
    int i = blockIdx.x * 256 + threadIdx.x;
    if (i < total4) {
        float4 v = ((const float4*)x)[i];
        half4v h;
        h[0] = (_Float16)v.x; h[1] = (_Float16)v.y; h[2] = (_Float16)v.z; h[3] = (_Float16)v.w;
        *(half4v*)(xh + (size_t)i * 4) = h;
    }
}

// W [128][nout] fp32 -> Wt [nout][128] fp16 (k contiguous)
__global__ void conv_w_kernel(const float* __restrict__ W, _Float16* __restrict__ Wt, int nout) {
    int idx = blockIdx.x * 256 + threadIdx.x;  // n*128 + k
    if (idx < nout * 128) {
        int nn = idx >> 7, k = idx & 127;
        Wt[idx] = (_Float16)W[k * nout + nn];
    }
}

// ---- fp16 MFMA GEMM: g[r][c] = dinv[r] * sum_k A[r][k]*W[k][c], K=128 -------
// Block 256 thr = 4 waves (2x2), BM=BN=128, full K staged in LDS (one barrier).
// LDS tiles k-contiguous, +8 half pad -> 272B row stride -> only 2-way bank
// aliasing on ds_read_b128 (free per m136).
// MFMA layouts (verified m89/m120): A[m=lane&15][k=(lane>>4)*8+j],
// B[k=(lane>>4)*8+j][n=lane&15] (stored as Bt[n][k]), D[row=(lane>>4)*4+reg][col=lane&15].
__global__ __launch_bounds__(256) void gemm_f16_kernel(const _Float16* __restrict__ A,   // [n][128]
                                                       const _Float16* __restrict__ Bt,  // [nout][128]
                                                       const float* __restrict__ dinv,
                                                       _Float16* __restrict__ g,         // [n][nout]
                                                       int n, int nout) {
    __shared__ _Float16 As[128][136];
    __shared__ _Float16 Bs[128][136];
    int t = threadIdx.x;
    int row0 = blockIdx.x * 128;
    int col0 = blockIdx.y * 128;

#pragma unroll
    for (int i = 0; i < 8; i++) {  // A: 128 rows x 16B chunks
        int c = i * 256 + t;
        int r = c >> 4, seg = c & 15;
        int gr = row0 + r;
        if (gr >= n) gr = n - 1;  // clamp: extra rows never stored
        uint4 v = *(const uint4*)(A + (size_t)gr * 128 + seg * 8);
        *(uint4*)(&As[r][seg * 8]) = v;
    }
#pragma unroll
    for (int i = 0; i < 8; i++) {  // B tile
        int c = i * 256 + t;
        int r = c >> 4, seg = c & 15;
        uint4 v = *(const uint4*)(Bt + (size_t)(col0 + r) * 128 + seg * 8);
        *(uint4*)(&Bs[r][seg * 8]) = v;
    }
    __syncthreads();

    int wid = t >> 6, lane = t & 63;
    int wm = wid >> 1, wn = wid & 1;
    int quad = lane >> 4, l16 = lane & 15;

    floatx4 acc[4][4];
#pragma unroll
    for (int mt = 0; mt < 4; mt++)
#pragma unroll
        for (int nt = 0; nt < 4; nt++) acc[mt][nt] = (floatx4){0.f, 0.f, 0.f, 0.f};

#pragma unroll
    for (int ks = 0; ks < 4; ks++) {
        int k0 = ks * 32 + quad * 8;
        half8 a[4], b[4];
#pragma unroll
        for (int mt = 0; mt < 4; mt++)
            a[mt] = *(const half8*)(&As[wm * 64 + mt * 16 + l16][k0]);
#pragma unroll
        for (int nt = 0; nt < 4; nt++)
            b[nt] = *(const half8*)(&Bs[wn * 64 + nt * 16 + l16][k0]);
#pragma unroll
        for (int mt = 0; mt < 4; mt++)
#pragma unroll
            for (int nt = 0; nt < 4; nt++)
                acc[mt][nt] = __builtin_amdgcn_mfma_f32_16x16x32_f16(a[mt], b[nt], acc[mt][nt], 0, 0, 0);
    }

#pragma unroll
    for (int mt = 0; mt < 4; mt++) {
        int rbase = row0 + wm * 64 + mt * 16 + quad * 4;
#pragma unroll
        for (int reg = 0; reg < 4; reg++) {
            int r = rbase + reg;
            if (r < n) {
                float dv = dinv[r];
#pragma unroll
                for (int nt = 0; nt < 4; nt++) {
                    int cc = col0 + wn * 64 + nt * 16 + l16;
                    g[(size_t)r * nout + cc] = (_Float16)(acc[mt][nt][reg] * dv);
                }
            }
        }
    }
}

// ---- gather aggregation, fp16 rows, fp32 accumulate ------------------------
// layer 1: F=128, out fp16 (feeds gemm2)
__global__ __launch_bounds__(256) void agg1_kernel(const _Float16* __restrict__ g,
                                                   const int* __restrict__ rowstart,
                                                   const int* __restrict__ csr,
                                                   const float* __restrict__ dinv,
                                                   const float* __restrict__ bias,
                                                   _Float16* __restrict__ out, int n) {
    int wid = (blockIdx.x * blockDim.x + threadIdx.x) >> 6;
    int lane = threadIdx.x & 63;
    if (wid >= n) return;
    int beg = rowstart[wid], end = rowstart[wid + 1];

    half2v sv = *(const half2v*)(g + (size_t)wid * 128 + lane * 2);
    float a0 = (float)sv[0], a1 = (float)sv[1];

    int e = beg;
    int u_next = (e < end) ? csr[e] : 0;
    while (e < end) {
        int u = u_next;
        ++e;
        if (e < end) u_next = csr[e];
        half2v v = *(const half2v*)(g + (size_t)u * 128 + lane * 2);
        a0 += (float)v[0];
        a1 += (float)v[1];
    }
    float dv = dinv[wid];
    half2v o;
    o[0] = (_Float16)fmaxf(fmaf(a0, dv, bias[lane * 2 + 0]), 0.f);
    o[1] = (_Float16)fmaxf(fmaf(a1, dv, bias[lane * 2 + 1]), 0.f);
    *(half2v*)(out + (size_t)wid * 128 + lane * 2) = o;
}

// layer 2: F=256, out fp32 (final output)
__global__ __launch_bounds__(256) void agg2_kernel(const _Float16* __restrict__ g,
                                                   const int* __restrict__ rowstart,
                                                   const int* __restrict__ csr,
                                                   const float* __restrict__ dinv,
                                                   const float* __restrict__ bias,
                                                   float* __restrict__ out, int n) {
    int wid = (blockIdx.x * blockDim.x + threadIdx.x) >> 6;
    int lane = threadIdx.x & 63;
    if (wid >= n) return;
    int beg = rowstart[wid], end = rowstart[wid + 1];

    half4v sv = *(const half4v*)(g + (size_t)wid * 256 + lane * 4);
    float a0 = (float)sv[0], a1 = (float)sv[1], a2 = (float)sv[2], a3 = (float)sv[3];

    int e = beg;
    int u_next = (e < end) ? csr[e] : 0;
    while (e < end) {
        int u = u_next;
        ++e;
        if (e < end) u_next = csr[e];
        half4v v = *(const half4v*)(g + (size_t)u * 256 + lane * 4);
        a0 += (float)v[0];
        a1 += (float)v[1];
        a2 += (float)v[2];
        a3 += (float)v[3];
    }
    float dv = dinv[wid];
    float4 o;
    o.x = fmaxf(fmaf(a0, dv, bias[lane * 4 + 0]), 0.f);
    o.y = fmaxf(fmaf(a1, dv, bias[lane * 4 + 1]), 0.f);
    o.z = fmaxf(fmaf(a2, dv, bias[lane * 4 + 2]), 0.f);
    o.w = fmaxf(fmaf(a3, dv, bias[lane * 4 + 3]), 0.f);
    *(float4*)(out + (size_t)wid * 256 + lane * 4) = o;
}

extern "C" void kernel_launch(void* const* d_in, const int* in_sizes, int n_in,
                              void* d_out, int out_size, void* d_ws, size_t ws_size,
                              hipStream_t stream) {
    const float* x  = (const float*)d_in[0];
    const int*   ei = (const int*)d_in[1];
    const float* W1 = (const float*)d_in[2];
    const float* b1 = (const float*)d_in[3];
    const float* W2 = (const float*)d_in[4];
    const float* b2 = (const float*)d_in[5];
    float* out = (float*)d_out;

    int N = in_sizes[0] / 128;   // 50000
    int E = in_sizes[1] / 2;     // 800000
    const int* src = ei;
    const int* dst = ei + E;

    char* w = (char*)d_ws;
    size_t off = 0;
    auto alloc = [&](size_t bytes) -> char* {
        char* p = w + off;
        off = (off + bytes + 255) & ~(size_t)255;
        return p;
    };
    int*      deg      = (int*)alloc((size_t)N * 4);
    int*      rowstart = (int*)alloc((size_t)(N + 1) * 4);
    int*      cursor   = (int*)alloc((size_t)N * 4);
    int*      partial  = (int*)alloc(256 * 4);
    float*    dinv     = (float*)alloc((size_t)N * 4);
    int*      csr      = (int*)alloc((size_t)E * 4);
    _Float16* xh       = (_Float16*)alloc((size_t)N * 128 * 2);
    _Float16* wt1      = (_Float16*)alloc((size_t)128 * 128 * 2);
    _Float16* wt2      = (_Float16*)alloc((size_t)256 * 128 * 2);
    _Float16* o1h      = (_Float16*)alloc((size_t)N * 128 * 2);
    _Float16* gbuf     = (_Float16*)alloc((size_t)N * 256 * 2);

    int nb_n = (N + 255) / 256;
    int nb_e = (E + 255) / 256;

    hipLaunchKernelGGL(init_deg_kernel,      dim3(nb_n), dim3(256), 0, stream, deg, N);
    hipLaunchKernelGGL(count_deg_kernel,     dim3(nb_e), dim3(256), 0, stream, dst, deg, E);
    hipLaunchKernelGGL(dinv_kernel,          dim3(nb_n), dim3(256), 0, stream, deg, dinv, N);
    hipLaunchKernelGGL(partial_sum_kernel,   dim3(nb_n), dim3(256), 0, stream, deg, partial, N);
    hipLaunchKernelGGL(scan_partials_kernel, dim3(1),    dim3(256), 0, stream, partial, nb_n);
    hipLaunchKernelGGL(scan_final_kernel,    dim3(nb_n), dim3(256), 0, stream, deg, partial, rowstart, cursor, N, E);
    hipLaunchKernelGGL(fill_csr_kernel,      dim3(nb_e), dim3(256), 0, stream, src, dst, cursor, csr, E);

    int total4 = N * 128 / 4;
    hipLaunchKernelGGL(conv_x_kernel, dim3((total4 + 255) / 256), dim3(256), 0, stream, x, xh, total4);
    hipLaunchKernelGGL(conv_w_kernel, dim3((128 * 128 + 255) / 256), dim3(256), 0, stream, W1, wt1, 128);
    hipLaunchKernelGGL(conv_w_kernel, dim3((256 * 128 + 255) / 256), dim3(256), 0, stream, W2, wt2, 256);

    int gbm = (N + 127) / 128;
    // layer 1
    hipLaunchKernelGGL(gemm_f16_kernel, dim3(gbm, 1), dim3(256), 0, stream, xh, wt1, dinv, gbuf, N, 128);
    hipLaunchKernelGGL(agg1_kernel, dim3((N + 3) / 4), dim3(256), 0, stream, gbuf, rowstart, csr, dinv, b1, o1h, N);
    // layer 2
    hipLaunchKernelGGL(gemm_f16_kernel, dim3(gbm, 2), dim3(256), 0, stream, o1h, wt2, dinv, gbuf, N, 256);
    hipLaunchKernelGGL(agg2_kernel, dim3((N + 3) / 4), dim3(256), 0, stream, gbuf, rowstart, csr, dinv, b2, out, N);
}

// Round 3
// 281.543 us; speedup vs baseline: 1.6742x; 1.1840x over previous
//
#include <hip/hip_runtime.h>

// ---------------------------------------------------------------------------
// 2-layer GCN, R3: aggregate-then-GEMM (linearity: agg commutes with @W),
// so BOTH gathers run in 128-dim fp16 (256B rows). Gather kernel uses
// 2 edges/wave-iteration (half-wave per row) + 2x unroll -> 4 loads in
// flight, attacking the R2 latency-bound profile (VALUBusy 30%, 5.8 TB/s
// delivered but only 43% HBM).
//   xs = fp16(x * dinv)
//   q1 = fp16(dinv * (xs_self + sum xs[u]))        [agg128]
//   p2 = fp16(relu(q1@W1 + b1) * dinv)             [gemm, fused epilogue]
//   q2 = fp16(dinv * (p2_self + sum p2[u]))        [agg128]
//   out = relu(q2@W2 + b2)  fp32                   [gemm]
// ---------------------------------------------------------------------------

typedef __attribute__((ext_vector_type(8))) _Float16 half8;
typedef __attribute__((ext_vector_type(4))) _Float16 half4v;
typedef __attribute__((ext_vector_type(4))) float floatx4;

__global__ void init_deg_kernel(int* __restrict__ deg, int n) {
    int i = blockIdx.x * blockDim.x + threadIdx.x;
    if (i < n) deg[i] = 0;
}

__global__ void count_deg_kernel(const int* __restrict__ dst, int* __restrict__ deg, int E) {
    int e = blockIdx.x * blockDim.x + threadIdx.x;
    if (e < E) atomicAdd(&deg[dst[e]], 1);
}

// ---- scan of deg -> rowstart/cursor, plus dinv = rsqrt(deg+1) --------------
__global__ void partial_sum_kernel(const int* __restrict__ deg, int* __restrict__ partial, int n) {
    __shared__ int sd[256];
    int t = threadIdx.x;
    int i = blockIdx.x * 256 + t;
    sd[t] = (i < n) ? deg[i] : 0;
    __syncthreads();
    for (int off = 128; off > 0; off >>= 1) {
        if (t < off) sd[t] += sd[t + off];
        __syncthreads();
    }
    if (t == 0) partial[blockIdx.x] = sd[0];
}

__global__ void scan_partials_kernel(int* __restrict__ partial, int nb) {
    __shared__ int sd[256];
    int t = threadIdx.x;
    int v = (t < nb) ? partial[t] : 0;
    sd[t] = v;
    __syncthreads();
    for (int off = 1; off < 256; off <<= 1) {
        int x = (t >= off) ? sd[t - off] : 0;
        __syncthreads();
        sd[t] += x;
        __syncthreads();
    }
    if (t < nb) partial[t] = sd[t] - v;  // exclusive
}

__global__ void scan_final_kernel(const int* __restrict__ deg, const int* __restrict__ partial,
                                  int* __restrict__ rowstart, int* __restrict__ cursor,
                                  float* __restrict__ dinv, int n, int E) {
    __shared__ int sd[256];
    int t = threadIdx.x;
    int b = blockIdx.x;
    int i = b * 256 + t;
    int v = (i < n) ? deg[i] : 0;
    sd[t] = v;
    __syncthreads();
    for (int off = 1; off < 256; off <<= 1) {
        int x = (t >= off) ? sd[t - off] : 0;
        __syncthreads();
        sd[t] += x;
        __syncthreads();
    }
    int excl = partial[b] + sd[t] - v;
    if (i < n) {
        rowstart[i] = excl;
        cursor[i] = excl;
        dinv[i] = rsqrtf((float)(v + 1));
    }
    if (i == 0) rowstart[n] = E;
}

__global__ void fill_csr_kernel(const int* __restrict__ src, const int* __restrict__ dst,
                                int* __restrict__ cursor, int* __restrict__ csr, int E) {
    int e = blockIdx.x * blockDim.x + threadIdx.x;
    if (e < E) {
        int d = dst[e];
        int pos = atomicAdd(&cursor[d], 1);
        csr[pos] = src[e];
    }
}

// ---- converts ---------------------------------------------------------------
// xs = fp16(x * dinv[row]); 4 floats per thread
__global__ void conv_xs_kernel(const float* __restrict__ x, const float* __restrict__ dinv,
                               _Float16* __restrict__ xs, int total4) {
    int i = blockIdx.x * 256 + threadIdx.x;
    if (i < total4) {
        int row = i >> 5;  // 32 float4 per 128-row
        float dv = dinv[row];
        float4 v = ((const float4*)x)[i];
        half4v h;
        h[0] = (_Float16)(v.x * dv); h[1] = (_Float16)(v.y * dv);
        h[2] = (_Float16)(v.z * dv); h[3] = (_Float16)(v.w * dv);
        *(half4v*)(xs + (size_t)i * 4) = h;
    }
}

// W1 [128][128] + W2 [128][256] fp32 -> wt1 [128][128], wt2 [256][128] fp16 (k contiguous)
__global__ void conv_w_kernel(const float* __restrict__ W1, const float* __restrict__ W2,
                              _Float16* __restrict__ wt1, _Float16* __restrict__ wt2) {
    int idx = blockIdx.x * 256 + threadIdx.x;  // n*128 + k
    if (idx < 128 * 128) {
        int nn = idx >> 7, k = idx & 127;
        wt1[idx] = (_Float16)W1[k * 128 + nn];
    } else if (idx < (128 + 256) * 128) {
        int j = idx - 128 * 128;
        int nn = j >> 7, k = j & 127;
        wt2[j] = (_Float16)W2[k * 256 + nn];
    }
}

// ---- 128-dim gather aggregation --------------------------------------------
// q[v] = fp16( dinv[v] * (g[v] + sum_{u->v} g[u]) ),  g rows 128 fp16 (256B).
// One wave per node; half-wave (32 lanes x 8B) per row; 2 edges per trip,
// unrolled x2 => 4 row-loads in flight. Butterfly xor-32 combines halves.
__global__ __launch_bounds__(256) void agg128_kernel(const _Float16* __restrict__ g,
                                                     const int* __restrict__ rowstart,
                                                     const int* __restrict__ csr,
                                                     const float* __restrict__ dinv,
                                                     _Float16* __restrict__ out, int n) {
    int wid = (blockIdx.x * blockDim.x + threadIdx.x) >> 6;
    int lane = threadIdx.x & 63;
    if (wid >= n) return;
    int half = lane >> 5, l32 = lane & 31;
    int beg = rowstart[wid], end = rowstart[wid + 1];

    float a0 = 0.f, a1 = 0.f, a2 = 0.f, a3 = 0.f;
    if (half == 0) {  // self term once
        half4v v = *(const half4v*)(g + (size_t)wid * 128 + l32 * 4);
        a0 = (float)v[0]; a1 = (float)v[1]; a2 = (float)v[2]; a3 = (float)v[3];
    }
    int e = beg + half;
    for (; e + 2 < end; e += 4) {  // 2 rows per half-wave in flight
        int u0 = csr[e];
        int u1 = csr[e + 2];
        half4v v0 = *(const half4v*)(g + (size_t)u0 * 128 + l32 * 4);
        half4v v1 = *(const half4v*)(g + (size_t)u1 * 128 + l32 * 4);
        a0 += (float)v0[0] + (float)v1[0];
        a1 += (float)v0[1] + (float)v1[1];
        a2 += (float)v0[2] + (float)v1[2];
        a3 += (float)v0[3] + (float)v1[3];
    }
    for (; e < end; e += 2) {
        int u = csr[e];
        half4v v = *(const half4v*)(g + (size_t)u * 128 + l32 * 4);
        a0 += (float)v[0]; a1 += (float)v[1]; a2 += (float)v[2]; a3 += (float)v[3];
    }
    // combine the two half-wave partials
    a0 += __shfl_xor(a0, 32);
    a1 += __shfl_xor(a1, 32);
    a2 += __shfl_xor(a2, 32);
    a3 += __shfl_xor(a3, 32);
    if (half == 0) {
        float dv = dinv[wid];
        half4v o;
        o[0] = (_Float16)(a0 * dv); o[1] = (_Float16)(a1 * dv);
        o[2] = (_Float16)(a2 * dv); o[3] = (_Float16)(a3 * dv);
        *(half4v*)(out + (size_t)wid * 128 + l32 * 4) = o;
    }
}

// ---- fp16 MFMA GEMM, K=128, BM=BN=128, fused epilogue ----------------------
// HALF_OUT: out = fp16(relu(acc+bias)*dinv)   else: out = fp32 relu(acc+bias)
// MFMA layouts (verified m89/m120): A[m=lane&15][k=(lane>>4)*8+j],
// B as Bt[n][k], D[row=(lane>>4)*4+reg][col=lane&15].
template <bool HALF_OUT>
__global__ __launch_bounds__(256) void gemm_kernel(const _Float16* __restrict__ A,   // [n][128]
                                                   const _Float16* __restrict__ Bt,  // [nout][128]
                                                   const float* __restrict__ bias,
                                                   const float* __restrict__ dinv,
                                                   void* __restrict__ outp,
                                                   int n, int nout) {
    __shared__ _Float16 As[128][136];
    __shared__ _Float16 Bs[128][136];
    int t = threadIdx.x;
    int row0 = blockIdx.x * 128;
    int col0 = blockIdx.y * 128;

#pragma unroll
    for (int i = 0; i < 8; i++) {
        int c = i * 256 + t;
        int r = c >> 4, seg = c & 15;
        int gr = row0 + r;
        if (gr >= n) gr = n - 1;  // clamp; extra rows never stored
        uint4 v = *(const uint4*)(A + (size_t)gr * 128 + seg * 8);
        *(uint4*)(&As[r][seg * 8]) = v;
    }
#pragma unroll
    for (int i = 0; i < 8; i++) {
        int c = i * 256 + t;
        int r = c >> 4, seg = c & 15;
        uint4 v = *(const uint4*)(Bt + (size_t)(col0 + r) * 128 + seg * 8);
        *(uint4*)(&Bs[r][seg * 8]) = v;
    }
    __syncthreads();

    int wid = t >> 6, lane = t & 63;
    int wm = wid >> 1, wn = wid & 1;
    int quad = lane >> 4, l16 = lane & 15;

    floatx4 acc[4][4];
#pragma unroll
    for (int mt = 0; mt < 4; mt++)
#pragma unroll
        for (int nt = 0; nt < 4; nt++) acc[mt][nt] = (floatx4){0.f, 0.f, 0.f, 0.f};

#pragma unroll
    for (int ks = 0; ks < 4; ks++) {
        int k0 = ks * 32 + quad * 8;
        half8 a[4], b[4];
#pragma unroll
        for (int mt = 0; mt < 4; mt++)
            a[mt] = *(const half8*)(&As[wm * 64 + mt * 16 + l16][k0]);
#pragma unroll
        for (int nt = 0; nt < 4; nt++)
            b[nt] = *(const half8*)(&Bs[wn * 64 + nt * 16 + l16][k0]);
#pragma unroll
        for (int mt = 0; mt < 4; mt++)
#pragma unroll
            for (int nt = 0; nt < 4; nt++)
                acc[mt][nt] = __builtin_amdgcn_mfma_f32_16x16x32_f16(a[mt], b[nt], acc[mt][nt], 0, 0, 0);
    }

#pragma unroll
    for (int mt = 0; mt < 4; mt++) {
        int rbase = row0 + wm * 64 + mt * 16 + quad * 4;
#pragma unroll
        for (int reg = 0; reg < 4; reg++) {
            int r = rbase + reg;
            if (r < n) {
                float dv = HALF_OUT ? dinv[r] : 1.f;
#pragma unroll
                for (int nt = 0; nt < 4; nt++) {
                    int cc = col0 + wn * 64 + nt * 16 + l16;
                    float val = fmaxf(acc[mt][nt][reg] + bias[cc], 0.f);
                    if (HALF_OUT)
                        ((_Float16*)outp)[(size_t)r * nout + cc] = (_Float16)(val * dv);
                    else
                        ((float*)outp)[(size_t)r * nout + cc] = val;
                }
            }
        }
    }
}

extern "C" void kernel_launch(void* const* d_in, const int* in_sizes, int n_in,
                              void* d_out, int out_size, void* d_ws, size_t ws_size,
                              hipStream_t stream) {
    const float* x  = (const float*)d_in[0];
    const int*   ei = (const int*)d_in[1];
    const float* W1 = (const float*)d_in[2];
    const float* b1 = (const float*)d_in[3];
    const float* W2 = (const float*)d_in[4];
    const float* b2 = (const float*)d_in[5];
    float* out = (float*)d_out;

    int N = in_sizes[0] / 128;   // 50000
    int E = in_sizes[1] / 2;     // 800000
    const int* src = ei;
    const int* dst = ei + E;

    char* w = (char*)d_ws;
    size_t off = 0;
    auto alloc = [&](size_t bytes) -> char* {
        char* p = w + off;
        off = (off + bytes + 255) & ~(size_t)255;
        return p;
    };
    int*      deg      = (int*)alloc((size_t)N * 4);
    int*      rowstart = (int*)alloc((size_t)(N + 1) * 4);
    int*      cursor   = (int*)alloc((size_t)N * 4);
    int*      partial  = (int*)alloc(256 * 4);
    float*    dinv     = (float*)alloc((size_t)N * 4);
    int*      csr      = (int*)alloc((size_t)E * 4);
    _Float16* xs       = (_Float16*)alloc((size_t)N * 128 * 2);
    _Float16* wt1      = (_Float16*)alloc((size_t)128 * 128 * 2);
    _Float16* wt2      = (_Float16*)alloc((size_t)256 * 128 * 2);
    _Float16* q1       = (_Float16*)alloc((size_t)N * 128 * 2);
    _Float16* p2       = (_Float16*)alloc((size_t)N * 128 * 2);
    _Float16* q2       = (_Float16*)alloc((size_t)N * 128 * 2);

    int nb_n = (N + 255) / 256;
    int nb_e = (E + 255) / 256;

    hipLaunchKernelGGL(init_deg_kernel,      dim3(nb_n), dim3(256), 0, stream, deg, N);
    hipLaunchKernelGGL(count_deg_kernel,     dim3(nb_e), dim3(256), 0, stream, dst, deg, E);
    hipLaunchKernelGGL(partial_sum_kernel,   dim3(nb_n), dim3(256), 0, stream, deg, partial, N);
    hipLaunchKernelGGL(scan_partials_kernel, dim3(1),    dim3(256), 0, stream, partial, nb_n);
    hipLaunchKernelGGL(scan_final_kernel,    dim3(nb_n), dim3(256), 0, stream, deg, partial, rowstart, cursor, dinv, N, E);
    hipLaunchKernelGGL(fill_csr_kernel,      dim3(nb_e), dim3(256), 0, stream, src, dst, cursor, csr, E);

    int total4 = N * 128 / 4;
    hipLaunchKernelGGL(conv_xs_kernel, dim3((total4 + 255) / 256), dim3(256), 0, stream, x, dinv, xs, total4);
    hipLaunchKernelGGL(conv_w_kernel, dim3((384 * 128 + 255) / 256), dim3(256), 0, stream, W1, W2, wt1, wt2);

    int gbm = (N + 127) / 128;
    int nb_agg = (N + 3) / 4;
    // layer 1
    hipLaunchKernelGGL(agg128_kernel, dim3(nb_agg), dim3(256), 0, stream, xs, rowstart, csr, dinv, q1, N);
    hipLaunchKernelGGL((gemm_kernel<true>), dim3(gbm, 1), dim3(256), 0, stream, q1, wt1, b1, dinv, (void*)p2, N, 128);
    // layer 2
    hipLaunchKernelGGL(agg128_kernel, dim3(nb_agg), dim3(256), 0, stream, p2, rowstart, csr, dinv, q2, N);
    hipLaunchKernelGGL((gemm_kernel<false>), dim3(gbm, 2), dim3(256), 0, stream, q2, wt2, b2, dinv, (void*)out, N, 256);
}

// Round 4
// 229.682 us; speedup vs baseline: 2.0523x; 1.2258x over previous
//
#include <hip/hip_runtime.h>

// ---------------------------------------------------------------------------
// 2-layer GCN, R4. Pipeline (aggregate-then-GEMM, both gathers 128-dim fp16):
//   CSR build: bucketed two-level (LDS atomics + windowed writes), replacing
//   the R3 global-atomic fill (48us, 51MB partial-line WRITE for 3.2MB csr).
//   xs = fp16(x*dinv)  [fused into build]
//   q1 = fp16(dinv*(xs_self + sum xs[u]))   [agg128, quarter-wave rows]
//   p2 = fp16(relu(q1@W1+b1)*dinv)          [MFMA gemm, fused epilogue]
//   q2 = fp16(dinv*(p2_self + sum p2[u]))   [agg128]
//   out = relu(q2@W2+b2) fp32               [MFMA gemm]
// ---------------------------------------------------------------------------

typedef __attribute__((ext_vector_type(8))) _Float16 half8;
typedef __attribute__((ext_vector_type(4))) _Float16 half4v;
typedef __attribute__((ext_vector_type(4))) float floatx4;

#define BSHIFT 7
#define BNODES 128   // nodes per bucket = 1<<BSHIFT

// ---- conv_w + zero bucket_cnt (independent of everything, runs first) ------
// W1 [128][128], W2 [128][256] fp32 -> wt1 [128][128], wt2 [256][128] fp16
__global__ void conv_w_init_kernel(const float* __restrict__ W1, const float* __restrict__ W2,
                                   _Float16* __restrict__ wt1, _Float16* __restrict__ wt2,
                                   int* __restrict__ bucket_cnt, int NB) {
    int idx = blockIdx.x * 256 + threadIdx.x;
    if (idx < NB) bucket_cnt[idx] = 0;
    if (idx < 128 * 128) {
        int nn = idx >> 7, k = idx & 127;
        wt1[idx] = (_Float16)W1[k * 128 + nn];
    } else if (idx < (128 + 256) * 128) {
        int j = idx - 128 * 128;
        int nn = j >> 7, k = j & 127;
        wt2[j] = (_Float16)W2[k * 256 + nn];
    }
}

// ---- Phase A1: coarse bucket counts via per-block LDS histogram ------------
__global__ __launch_bounds__(256) void bucket_count_kernel(const int* __restrict__ dst,
                                                           int* __restrict__ bucket_cnt,
                                                           int E, int chunk, int NB) {
    extern __shared__ int hist[];  // NB ints
    int t = threadIdx.x;
    for (int i = t; i < NB; i += 256) hist[i] = 0;
    __syncthreads();
    int cbeg = blockIdx.x * chunk;
    int cend = min(E, cbeg + chunk);
    for (int e = cbeg + t; e < cend; e += 256)
        atomicAdd(&hist[dst[e] >> BSHIFT], 1);
    __syncthreads();
    for (int i = t; i < NB; i += 256)
        if (hist[i]) atomicAdd(&bucket_cnt[i], hist[i]);
}

// ---- Phase A2: tiny scan of NB bucket counts -------------------------------
__global__ void bucket_scan_kernel(const int* __restrict__ bucket_cnt,
                                   int* __restrict__ bucket_base,
                                   int* __restrict__ bucket_cursor, int NB) {
    __shared__ int sd[512];
    int t = threadIdx.x;
    int v = (t < NB) ? bucket_cnt[t] : 0;
    sd[t] = v;
    __syncthreads();
    for (int off = 1; off < 512; off <<= 1) {
        int x = (t >= off) ? sd[t - off] : 0;
        __syncthreads();
        sd[t] += x;
        __syncthreads();
    }
    if (t < NB) {
        int excl = sd[t] - v;
        bucket_base[t] = excl;
        bucket_cursor[t] = excl;
        if (t == NB - 1) bucket_base[NB] = sd[t];
    }
}

// ---- Phase A3: scatter (src,dst) into bucket runs --------------------------
// Block reserves per-bucket ranges with ONE global atomic per (block,bucket);
// within-block ranks via LDS atomics -> writes to a bucket are consecutive.
__global__ __launch_bounds__(256) void bucket_scatter_kernel(const int* __restrict__ src,
                                                             const int* __restrict__ dst,
                                                             int* __restrict__ bucket_cursor,
                                                             uint2* __restrict__ bucketed,
                                                             int E, int chunk, int NB) {
    extern __shared__ int sh[];       // hist | base_loc | cur2  (3*NB ints)
    int* hist = sh;
    int* base_loc = sh + NB;
    int* cur2 = sh + 2 * NB;
    int t = threadIdx.x;
    for (int i = t; i < NB; i += 256) { hist[i] = 0; cur2[i] = 0; }
    __syncthreads();
    int cbeg = blockIdx.x * chunk;
    int cend = min(E, cbeg + chunk);
    for (int e = cbeg + t; e < cend; e += 256)
        atomicAdd(&hist[dst[e] >> BSHIFT], 1);
    __syncthreads();
    for (int i = t; i < NB; i += 256) {
        int c = hist[i];
        base_loc[i] = c ? atomicAdd(&bucket_cursor[i], c) : 0;
    }
    __syncthreads();
    for (int e = cbeg + t; e < cend; e += 256) {
        int d = dst[e];
        int bkt = d >> BSHIFT;
        int r = atomicAdd(&cur2[bkt], 1);
        bucketed[base_loc[bkt] + r] = make_uint2((unsigned)src[e], (unsigned)d);
    }
}

// ---- Phase B: per-bucket CSR build + dinv + xs conversion ------------------
// One block per bucket (128 nodes, ~2k edges). All csr writes land in the
// bucket's contiguous window; all cursor atomics are LDS.
__global__ __launch_bounds__(256) void build_kernel(const uint2* __restrict__ bucketed,
                                                    const int* __restrict__ bucket_base,
                                                    const float* __restrict__ x,
                                                    int* __restrict__ rowstart,
                                                    float* __restrict__ dinv,
                                                    int* __restrict__ csr,
                                                    _Float16* __restrict__ xs,
                                                    int N, int E, int NB) {
    __shared__ int deg_loc[BNODES];
    __shared__ int tmp[BNODES];
    __shared__ int cur_loc[BNODES];
    __shared__ float dinv_loc[BNODES];
    int t = threadIdx.x;
    int b = blockIdx.x;
    int n0 = b << BSHIFT;
    int nodes_in = min(BNODES, N - n0);
    int wbeg = bucket_base[b];
    int wend = bucket_base[b + 1];

    if (t < BNODES) deg_loc[t] = 0;
    __syncthreads();
    for (int e = wbeg + t; e < wend; e += 256)
        atomicAdd(&deg_loc[bucketed[e].y & (BNODES - 1)], 1);
    __syncthreads();
    if (t < BNODES) tmp[t] = deg_loc[t];
    __syncthreads();
    for (int off = 1; off < BNODES; off <<= 1) {
        int v = 0;
        if (t < BNODES && t >= off) v = tmp[t - off];
        __syncthreads();
        if (t < BNODES) tmp[t] += v;
        __syncthreads();
    }
    if (t < BNODES) {
        int abs0 = wbeg + tmp[t] - deg_loc[t];
        cur_loc[t] = abs0;
        float dv = rsqrtf((float)(deg_loc[t] + 1));
        dinv_loc[t] = dv;
        if (t < nodes_in) {
            rowstart[n0 + t] = abs0;
            dinv[n0 + t] = dv;
        }
    }
    if (b == NB - 1 && t == 0) rowstart[N] = E;
    __syncthreads();
    // csr fill, windowed
    for (int e = wbeg + t; e < wend; e += 256) {
        uint2 u2 = bucketed[e];
        int pos = atomicAdd(&cur_loc[u2.y & (BNODES - 1)], 1);
        csr[pos] = (int)u2.x;
    }
    // xs = fp16(x * dinv) for this bucket's rows (coalesced float4)
    int total4 = nodes_in * 32;  // 32 float4 per 128-wide row
    const float4* x4 = (const float4*)(x + (size_t)n0 * 128);
    for (int i = t; i < total4; i += 256) {
        int row = i >> 5;
        float dv = dinv_loc[row];
        float4 v = x4[i];
        half4v h;
        h[0] = (_Float16)(v.x * dv); h[1] = (_Float16)(v.y * dv);
        h[2] = (_Float16)(v.z * dv); h[3] = (_Float16)(v.w * dv);
        *(half4v*)(xs + (size_t)n0 * 128 + (size_t)i * 4) = h;
    }
}

// ---- 128-dim gather aggregation, quarter-wave rows -------------------------
// q[v] = fp16( dinv[v] * (g[v] + sum_{u->v} g[u]) ); g rows = 256B fp16.
// 16 lanes x 16B per row -> 4 rows/wave-instruction; x2 unroll -> 8 in flight.
__global__ __launch_bounds__(256) void agg128_kernel(const _Float16* __restrict__ g,
                                                     const int* __restrict__ rowstart,
                                                     const int* __restrict__ csr,
                                                     const float* __restrict__ dinv,
                                                     _Float16* __restrict__ out, int n) {
    int wid = (blockIdx.x * blockDim.x + threadIdx.x) >> 6;
    int lane = threadIdx.x & 63;
    if (wid >= n) return;
    int q = lane >> 4, l16 = lane & 15;
    int beg = rowstart[wid], end = rowstart[wid + 1];

    float a[8] = {0.f, 0.f, 0.f, 0.f, 0.f, 0.f, 0.f, 0.f};
    if (q == 0) {  // self term
        half8 v = *(const half8*)(g + (size_t)wid * 128 + l16 * 8);
#pragma unroll
        for (int j = 0; j < 8; j++) a[j] = (float)v[j];
    }
    int e = beg + q;
    for (; e + 4 < end; e += 8) {
        int u0 = csr[e];
        int u1 = csr[e + 4];
        half8 v0 = *(const half8*)(g + (size_t)u0 * 128 + l16 * 8);
        half8 v1 = *(const half8*)(g + (size_t)u1 * 128 + l16 * 8);
#pragma unroll
        for (int j = 0; j < 8; j++) a[j] += (float)v0[j] + (float)v1[j];
    }
    for (; e < end; e += 4) {
        int u = csr[e];
        half8 v = *(const half8*)(g + (size_t)u * 128 + l16 * 8);
#pragma unroll
        for (int j = 0; j < 8; j++) a[j] += (float)v[j];
    }
#pragma unroll
    for (int j = 0; j < 8; j++) {
        a[j] += __shfl_xor(a[j], 16);
        a[j] += __shfl_xor(a[j], 32);
    }
    if (q == 0) {
        float dv = dinv[wid];
        half8 o;
#pragma unroll
        for (int j = 0; j < 8; j++) o[j] = (_Float16)(a[j] * dv);
        *(half8*)(out + (size_t)wid * 128 + l16 * 8) = o;
    }
}

// ---- fp16 MFMA GEMM, K=128, BM=BN=128, fused epilogue ----------------------
// HALF_OUT: out = fp16(relu(acc+bias)*dinv)   else: fp32 relu(acc+bias)
// MFMA layouts (m89/m120): A[m=lane&15][k=(lane>>4)*8+j], B as Bt[n][k],
// D[row=(lane>>4)*4+reg][col=lane&15].
template <bool HALF_OUT>
__global__ __launch_bounds__(256) void gemm_kernel(const _Float16* __restrict__ A,   // [n][128]
                                                   const _Float16* __restrict__ Bt,  // [nout][128]
                                                   const float* __restrict__ bias,
                                                   const float* __restrict__ dinv,
                                                   void* __restrict__ outp,
                                                   int n, int nout) {
    __shared__ _Float16 As[128][136];
    __shared__ _Float16 Bs[128][136];
    int t = threadIdx.x;
    int row0 = blockIdx.x * 128;
    int col0 = blockIdx.y * 128;

#pragma unroll
    for (int i = 0; i < 8; i++) {
        int c = i * 256 + t;
        int r = c >> 4, seg = c & 15;
        int gr = row0 + r;
        if (gr >= n) gr = n - 1;  // clamp; extra rows never stored
        uint4 v = *(const uint4*)(A + (size_t)gr * 128 + seg * 8);
        *(uint4*)(&As[r][seg * 8]) = v;
    }
#pragma unroll
    for (int i = 0; i < 8; i++) {
        int c = i * 256 + t;
        int r = c >> 4, seg = c & 15;
        uint4 v = *(const uint4*)(Bt + (size_t)(col0 + r) * 128 + seg * 8);
        *(uint4*)(&Bs[r][seg * 8]) = v;
    }
    __syncthreads();

    int wid = t >> 6, lane = t & 63;
    int wm = wid >> 1, wn = wid & 1;
    int quad = lane >> 4, l16 = lane & 15;

    floatx4 acc[4][4];
#pragma unroll
    for (int mt = 0; mt < 4; mt++)
#pragma unroll
        for (int nt = 0; nt < 4; nt++) acc[mt][nt] = (floatx4){0.f, 0.f, 0.f, 0.f};

#pragma unroll
    for (int ks = 0; ks < 4; ks++) {
        int k0 = ks * 32 + quad * 8;
        half8 a[4], b[4];
#pragma unroll
        for (int mt = 0; mt < 4; mt++)
            a[mt] = *(const half8*)(&As[wm * 64 + mt * 16 + l16][k0]);
#pragma unroll
        for (int nt = 0; nt < 4; nt++)
            b[nt] = *(const half8*)(&Bs[wn * 64 + nt * 16 + l16][k0]);
#pragma unroll
        for (int mt = 0; mt < 4; mt++)
#pragma unroll
            for (int nt = 0; nt < 4; nt++)
                acc[mt][nt] = __builtin_amdgcn_mfma_f32_16x16x32_f16(a[mt], b[nt], acc[mt][nt], 0, 0, 0);
    }

#pragma unroll
    for (int mt = 0; mt < 4; mt++) {
        int rbase = row0 + wm * 64 + mt * 16 + quad * 4;
#pragma unroll
        for (int reg = 0; reg < 4; reg++) {
            int r = rbase + reg;
            if (r < n) {
                float dv = HALF_OUT ? dinv[r] : 1.f;
#pragma unroll
                for (int nt = 0; nt < 4; nt++) {
                    int cc = col0 + wn * 64 + nt * 16 + l16;
                    float val = fmaxf(acc[mt][nt][reg] + bias[cc], 0.f);
                    if (HALF_OUT)
                        ((_Float16*)outp)[(size_t)r * nout + cc] = (_Float16)(val * dv);
                    else
                        ((float*)outp)[(size_t)r * nout + cc] = val;
                }
            }
        }
    }
}

extern "C" void kernel_launch(void* const* d_in, const int* in_sizes, int n_in,
                              void* d_out, int out_size, void* d_ws, size_t ws_size,
                              hipStream_t stream) {
    const float* x  = (const float*)d_in[0];
    const int*   ei = (const int*)d_in[1];
    const float* W1 = (const float*)d_in[2];
    const float* b1 = (const float*)d_in[3];
    const float* W2 = (const float*)d_in[4];
    const float* b2 = (const float*)d_in[5];
    float* out = (float*)d_out;

    int N = in_sizes[0] / 128;   // 50000
    int E = in_sizes[1] / 2;     // 800000
    const int* src = ei;
    const int* dst = ei + E;
    int NB = (N + BNODES - 1) >> BSHIFT;   // 391 buckets

    char* w = (char*)d_ws;
    size_t off = 0;
    auto alloc = [&](size_t bytes) -> char* {
        char* p = w + off;
        off = (off + bytes + 255) & ~(size_t)255;
        return p;
    };
    int*      bucket_cnt    = (int*)alloc((size_t)NB * 4);
    int*      bucket_base   = (int*)alloc((size_t)(NB + 1) * 4);
    int*      bucket_cursor = (int*)alloc((size_t)NB * 4);
    uint2*    bucketed      = (uint2*)alloc((size_t)E * 8);
    int*      rowstart      = (int*)alloc((size_t)(N + 1) * 4);
    float*    dinv          = (float*)alloc((size_t)N * 4);
    int*      csr           = (int*)alloc((size_t)E * 4);
    _Float16* wt1           = (_Float16*)alloc((size_t)128 * 128 * 2);
    _Float16* wt2           = (_Float16*)alloc((size_t)256 * 128 * 2);
    _Float16* xs            = (_Float16*)alloc((size_t)N * 128 * 2);
    _Float16* q1            = (_Float16*)alloc((size_t)N * 128 * 2);
    _Float16* p2            = (_Float16*)alloc((size_t)N * 128 * 2);
    _Float16* q2            = (_Float16*)alloc((size_t)N * 128 * 2);

    int chunk = (E + 255) / 256;          // edges per Phase-A block
    size_t lds1 = (size_t)NB * 4;         // bucket_count hist
    size_t lds3 = (size_t)NB * 12;        // bucket_scatter hist+base+cur

    hipLaunchKernelGGL(conv_w_init_kernel, dim3(192), dim3(256), 0, stream, W1, W2, wt1, wt2, bucket_cnt, NB);
    hipLaunchKernelGGL(bucket_count_kernel, dim3(256), dim3(256), lds1, stream, dst, bucket_cnt, E, chunk, NB);
    hipLaunchKernelGGL(bucket_scan_kernel, dim3(1), dim3(512), 0, stream, bucket_cnt, bucket_base, bucket_cursor, NB);
    hipLaunchKernelGGL(bucket_scatter_kernel, dim3(256), dim3(256), lds3, stream, src, dst, bucket_cursor, bucketed, E, chunk, NB);
    hipLaunchKernelGGL(build_kernel, dim3(NB), dim3(256), 0, stream, bucketed, bucket_base, x, rowstart, dinv, csr, xs, N, E, NB);

    int gbm = (N + 127) / 128;
    int nb_agg = (N + 3) / 4;
    // layer 1
    hipLaunchKernelGGL(agg128_kernel, dim3(nb_agg), dim3(256), 0, stream, xs, rowstart, csr, dinv, q1, N);
    hipLaunchKernelGGL((gemm_kernel<true>), dim3(gbm, 1), dim3(256), 0, stream, q1, wt1, b1, dinv, (void*)p2, N, 128);
    // layer 2
    hipLaunchKernelGGL(agg128_kernel, dim3(nb_agg), dim3(256), 0, stream, p2, rowstart, csr, dinv, q2, N);
    hipLaunchKernelGGL((gemm_kernel<false>), dim3(gbm, 2), dim3(256), 0, stream, q2, wt2, b2, dinv, (void*)out, N, 256);
}

// Round 5
// 224.844 us; speedup vs baseline: 2.0964x; 1.0215x over previous
//
#include <hip/hip_runtime.h>

// ---------------------------------------------------------------------------
// 2-layer GCN, R5. Pipeline (aggregate-then-GEMM, both gathers 128-dim fp16):
//   bucketed CSR build (LDS atomics, windowed writes), packed uint32 edge recs
//   xs = fp16(x*dinv)  [fused into build]
//   q1 = fp16(dinv*(xs_self + sum xs[u]))   [agg128, 16 rows in flight/wave]
//   p2 = fp16(relu(q1@W1+b1)*dinv)          [MFMA gemm, fused epilogue]
//   q2 = fp16(dinv*(p2_self + sum p2[u]))   [agg128]
//   out = relu(q2@W2+b2) fp32               [MFMA gemm]
// R4 post-mortem: all kernels < 41 us; aggs near fabric floor -> push ILP.
// ---------------------------------------------------------------------------

typedef __attribute__((ext_vector_type(8))) _Float16 half8;
typedef __attribute__((ext_vector_type(4))) _Float16 half4v;
typedef __attribute__((ext_vector_type(4))) float floatx4;

#define BSHIFT 7
#define BNODES 128   // nodes per bucket = 1<<BSHIFT

// ---- Phase A1 (+ W transpose in extra blocks) ------------------------------
// Blocks [0,256): per-block LDS histogram of dst>>7 -> bucket_cnt (global atomics
// once per (block,bucket)). Blocks [256,256+192): W1/W2 fp32 -> fp16 transposed.
__global__ __launch_bounds__(256) void count_conv_kernel(const int* __restrict__ dst,
                                                         int* __restrict__ bucket_cnt,
                                                         const float* __restrict__ W1,
                                                         const float* __restrict__ W2,
                                                         _Float16* __restrict__ wt1,
                                                         _Float16* __restrict__ wt2,
                                                         int E, int chunk, int NB) {
    int t = threadIdx.x;
    if (blockIdx.x >= 256) {
        int idx = (blockIdx.x - 256) * 256 + t;
        if (idx < 128 * 128) {
            int nn = idx >> 7, k = idx & 127;
            wt1[idx] = (_Float16)W1[k * 128 + nn];
        } else if (idx < (128 + 256) * 128) {
            int j = idx - 128 * 128;
            int nn = j >> 7, k = j & 127;
            wt2[j] = (_Float16)W2[k * 256 + nn];
        }
        return;
    }
    extern __shared__ int hist[];  // NB ints
    for (int i = t; i < NB; i += 256) hist[i] = 0;
    __syncthreads();
    int cbeg = blockIdx.x * chunk;
    int cend = min(E, cbeg + chunk);
    for (int e = cbeg + t; e < cend; e += 256)
        atomicAdd(&hist[dst[e] >> BSHIFT], 1);
    __syncthreads();
    for (int i = t; i < NB; i += 256)
        if (hist[i]) atomicAdd(&bucket_cnt[i], hist[i]);
}

// ---- Phase A2: tiny scan of NB bucket counts -------------------------------
__global__ void bucket_scan_kernel(const int* __restrict__ bucket_cnt,
                                   int* __restrict__ bucket_base,
                                   int* __restrict__ bucket_cursor, int NB) {
    __shared__ int sd[512];
    int t = threadIdx.x;
    int v = (t < NB) ? bucket_cnt[t] : 0;
    sd[t] = v;
    __syncthreads();
    for (int off = 1; off < 512; off <<= 1) {
        int x = (t >= off) ? sd[t - off] : 0;
        __syncthreads();
        sd[t] += x;
        __syncthreads();
    }
    if (t < NB) {
        int excl = sd[t] - v;
        bucket_base[t] = excl;
        bucket_cursor[t] = excl;
        if (t == NB - 1) bucket_base[NB] = sd[t];
    }
}

// ---- Phase A3: scatter packed (src | dst_low7<<16) into bucket runs --------
// One global atomic per (block,bucket) reserves a range; within-block ranks via
// LDS atomics -> a block's writes to each bucket are consecutive (line-friendly).
// Pack is valid because N=50000 < 65536.
__global__ __launch_bounds__(256) void bucket_scatter_kernel(const int* __restrict__ src,
                                                             const int* __restrict__ dst,
                                                             int* __restrict__ bucket_cursor,
                                                             unsigned* __restrict__ bucketed,
                                                             int E, int chunk, int NB) {
    extern __shared__ int sh[];       // hist | base_loc | cur2  (3*NB ints)
    int* hist = sh;
    int* base_loc = sh + NB;
    int* cur2 = sh + 2 * NB;
    int t = threadIdx.x;
    for (int i = t; i < NB; i += 256) { hist[i] = 0; cur2[i] = 0; }
    __syncthreads();
    int cbeg = blockIdx.x * chunk;
    int cend = min(E, cbeg + chunk);
    for (int e = cbeg + t; e < cend; e += 256)
        atomicAdd(&hist[dst[e] >> BSHIFT], 1);
    __syncthreads();
    for (int i = t; i < NB; i += 256) {
        int c = hist[i];
        base_loc[i] = c ? atomicAdd(&bucket_cursor[i], c) : 0;
    }
    __syncthreads();
    for (int e = cbeg + t; e < cend; e += 256) {
        int d = dst[e];
        int bkt = d >> BSHIFT;
        int r = atomicAdd(&cur2[bkt], 1);
        bucketed[base_loc[bkt] + r] =
            (unsigned)src[e] | ((unsigned)(d & (BNODES - 1)) << 16);
    }
}

// ---- Phase B: per-bucket CSR build + dinv + xs conversion ------------------
// One block per bucket (128 nodes, ~2k edges). All csr writes land in the
// bucket's contiguous window; all cursor atomics are LDS.
__global__ __launch_bounds__(256) void build_kernel(const unsigned* __restrict__ bucketed,
                                                    const int* __restrict__ bucket_base,
                                                    const float* __restrict__ x,
                                                    int* __restrict__ rowstart,
                                                    float* __restrict__ dinv,
                                                    int* __restrict__ csr,
                                                    _Float16* __restrict__ xs,
                                                    int N, int E, int NB) {
    __shared__ int deg_loc[BNODES];
    __shared__ int tmp[BNODES];
    __shared__ int cur_loc[BNODES];
    __shared__ float dinv_loc[BNODES];
    int t = threadIdx.x;
    int b = blockIdx.x;
    int n0 = b << BSHIFT;
    int nodes_in = min(BNODES, N - n0);
    int wbeg = bucket_base[b];
    int wend = bucket_base[b + 1];

    if (t < BNODES) deg_loc[t] = 0;
    __syncthreads();
    for (int e = wbeg + t; e < wend; e += 256)
        atomicAdd(&deg_loc[bucketed[e] >> 16], 1);
    __syncthreads();
    if (t < BNODES) tmp[t] = deg_loc[t];
    __syncthreads();
    for (int off = 1; off < BNODES; off <<= 1) {
        int v = 0;
        if (t < BNODES && t >= off) v = tmp[t - off];
        __syncthreads();
        if (t < BNODES) tmp[t] += v;
        __syncthreads();
    }
    if (t < BNODES) {
        int abs0 = wbeg + tmp[t] - deg_loc[t];
        cur_loc[t] = abs0;
        float dv = rsqrtf((float)(deg_loc[t] + 1));
        dinv_loc[t] = dv;
        if (t < nodes_in) {
            rowstart[n0 + t] = abs0;
            dinv[n0 + t] = dv;
        }
    }
    if (b == NB - 1 && t == 0) rowstart[N] = E;
    __syncthreads();
    // csr fill, windowed
    for (int e = wbeg + t; e < wend; e += 256) {
        unsigned u2 = bucketed[e];
        int pos = atomicAdd(&cur_loc[u2 >> 16], 1);
        csr[pos] = (int)(u2 & 0xFFFFu);
    }
    // xs = fp16(x * dinv) for this bucket's rows (coalesced float4)
    int total4 = nodes_in * 32;  // 32 float4 per 128-wide row
    const float4* x4 = (const float4*)(x + (size_t)n0 * 128);
    for (int i = t; i < total4; i += 256) {
        int row = i >> 5;
        float dv = dinv_loc[row];
        float4 v = x4[i];
        half4v h;
        h[0] = (_Float16)(v.x * dv); h[1] = (_Float16)(v.y * dv);
        h[2] = (_Float16)(v.z * dv); h[3] = (_Float16)(v.w * dv);
        *(half4v*)(xs + (size_t)n0 * 128 + (size_t)i * 4) = h;
    }
}

// ---- 128-dim gather aggregation, quarter-wave rows, 4x unroll --------------
// q[v] = fp16( dinv[v] * (g[v] + sum_{u->v} g[u]) ); g rows = 256B fp16.
// 16 lanes x 16B per row -> 4 rows/wave-instruction; x4 unroll -> 16 in flight.
// Avg degree 16 => the typical node completes in ONE unrolled iteration.
__global__ __launch_bounds__(256) void agg128_kernel(const _Float16* __restrict__ g,
                                                     const int* __restrict__ rowstart,
                                                     const int* __restrict__ csr,
                                                     const float* __restrict__ dinv,
                                                     _Float16* __restrict__ out, int n) {
    int wid = (blockIdx.x * blockDim.x + threadIdx.x) >> 6;
    int lane = threadIdx.x & 63;
    if (wid >= n) return;
    int q = lane >> 4, l16 = lane & 15;
    int beg = rowstart[wid], end = rowstart[wid + 1];

    float a[8] = {0.f, 0.f, 0.f, 0.f, 0.f, 0.f, 0.f, 0.f};
    if (q == 0) {  // self term
        half8 v = *(const half8*)(g + (size_t)wid * 128 + l16 * 8);
#pragma unroll
        for (int j = 0; j < 8; j++) a[j] = (float)v[j];
    }
    int e = beg + q;
    for (; e + 12 < end; e += 16) {   // 4 rows per quarter in flight
        int u0 = csr[e];
        int u1 = csr[e + 4];
        int u2 = csr[e + 8];
        int u3 = csr[e + 12];
        half8 v0 = *(const half8*)(g + (size_t)u0 * 128 + l16 * 8);
        half8 v1 = *(const half8*)(g + (size_t)u1 * 128 + l16 * 8);
        half8 v2 = *(const half8*)(g + (size_t)u2 * 128 + l16 * 8);
        half8 v3 = *(const half8*)(g + (size_t)u3 * 128 + l16 * 8);
#pragma unroll
        for (int j = 0; j < 8; j++)
            a[j] += ((float)v0[j] + (float)v1[j]) + ((float)v2[j] + (float)v3[j]);
    }
    for (; e + 4 < end; e += 8) {     // 2 rows in flight
        int u0 = csr[e];
        int u1 = csr[e + 4];
        half8 v0 = *(const half8*)(g + (size_t)u0 * 128 + l16 * 8);
        half8 v1 = *(const half8*)(g + (size_t)u1 * 128 + l16 * 8);
#pragma unroll
        for (int j = 0; j < 8; j++) a[j] += (float)v0[j] + (float)v1[j];
    }
    for (; e < end; e += 4) {
        int u = csr[e];
        half8 v = *(const half8*)(g + (size_t)u * 128 + l16 * 8);
#pragma unroll
        for (int j = 0; j < 8; j++) a[j] += (float)v[j];
    }
#pragma unroll
    for (int j = 0; j < 8; j++) {
        a[j] += __shfl_xor(a[j], 16);
        a[j] += __shfl_xor(a[j], 32);
    }
    if (q == 0) {
        float dv = dinv[wid];
        half8 o;
#pragma unroll
        for (int j = 0; j < 8; j++) o[j] = (_Float16)(a[j] * dv);
        *(half8*)(out + (size_t)wid * 128 + l16 * 8) = o;
    }
}

// ---- fp16 MFMA GEMM, K=128, BM=BN=128, fused epilogue ----------------------
// HALF_OUT: out = fp16(relu(acc+bias)*dinv)   else: fp32 relu(acc+bias)
// MFMA layouts (m89/m120): A[m=lane&15][k=(lane>>4)*8+j], B as Bt[n][k],
// D[row=(lane>>4)*4+reg][col=lane&15].
template <bool HALF_OUT>
__global__ __launch_bounds__(256) void gemm_kernel(const _Float16* __restrict__ A,   // [n][128]
                                                   const _Float16* __restrict__ Bt,  // [nout][128]
                                                   const float* __restrict__ bias,
                                                   const float* __restrict__ dinv,
                                                   void* __restrict__ outp,
                                                   int n, int nout) {
    __shared__ _Float16 As[128][136];
    __shared__ _Float16 Bs[128][136];
    int t = threadIdx.x;
    int row0 = blockIdx.x * 128;
    int col0 = blockIdx.y * 128;

#pragma unroll
    for (int i = 0; i < 8; i++) {
        int c = i * 256 + t;
        int r = c >> 4, seg = c & 15;
        int gr = row0 + r;
        if (gr >= n) gr = n - 1;  // clamp; extra rows never stored
        uint4 v = *(const uint4*)(A + (size_t)gr * 128 + seg * 8);
        *(uint4*)(&As[r][seg * 8]) = v;
    }
#pragma unroll
    for (int i = 0; i < 8; i++) {
        int c = i * 256 + t;
        int r = c >> 4, seg = c & 15;
        uint4 v = *(const uint4*)(Bt + (size_t)(col0 + r) * 128 + seg * 8);
        *(uint4*)(&Bs[r][seg * 8]) = v;
    }
    __syncthreads();

    int wid = t >> 6, lane = t & 63;
    int wm = wid >> 1, wn = wid & 1;
    int quad = lane >> 4, l16 = lane & 15;

    floatx4 acc[4][4];
#pragma unroll
    for (int mt = 0; mt < 4; mt++)
#pragma unroll
        for (int nt = 0; nt < 4; nt++) acc[mt][nt] = (floatx4){0.f, 0.f, 0.f, 0.f};

#pragma unroll
    for (int ks = 0; ks < 4; ks++) {
        int k0 = ks * 32 + quad * 8;
        half8 a[4], b[4];
#pragma unroll
        for (int mt = 0; mt < 4; mt++)
            a[mt] = *(const half8*)(&As[wm * 64 + mt * 16 + l16][k0]);
#pragma unroll
        for (int nt = 0; nt < 4; nt++)
            b[nt] = *(const half8*)(&Bs[wn * 64 + nt * 16 + l16][k0]);
#pragma unroll
        for (int mt = 0; mt < 4; mt++)
#pragma unroll
            for (int nt = 0; nt < 4; nt++)
                acc[mt][nt] = __builtin_amdgcn_mfma_f32_16x16x32_f16(a[mt], b[nt], acc[mt][nt], 0, 0, 0);
    }

#pragma unroll
    for (int mt = 0; mt < 4; mt++) {
        int rbase = row0 + wm * 64 + mt * 16 + quad * 4;
#pragma unroll
        for (int reg = 0; reg < 4; reg++) {
            int r = rbase + reg;
            if (r < n) {
                float dv = HALF_OUT ? dinv[r] : 1.f;
#pragma unroll
                for (int nt = 0; nt < 4; nt++) {
                    int cc = col0 + wn * 64 + nt * 16 + l16;
                    float val = fmaxf(acc[mt][nt][reg] + bias[cc], 0.f);
                    if (HALF_OUT)
                        ((_Float16*)outp)[(size_t)r * nout + cc] = (_Float16)(val * dv);
                    else
                        ((float*)outp)[(size_t)r * nout + cc] = val;
                }
            }
        }
    }
}

extern "C" void kernel_launch(void* const* d_in, const int* in_sizes, int n_in,
                              void* d_out, int out_size, void* d_ws, size_t ws_size,
                              hipStream_t stream) {
    const float* x  = (const float*)d_in[0];
    const int*   ei = (const int*)d_in[1];
    const float* W1 = (const float*)d_in[2];
    const float* b1 = (const float*)d_in[3];
    const float* W2 = (const float*)d_in[4];
    const float* b2 = (const float*)d_in[5];
    float* out = (float*)d_out;

    int N = in_sizes[0] / 128;   // 50000
    int E = in_sizes[1] / 2;     // 800000
    const int* src = ei;
    const int* dst = ei + E;
    int NB = (N + BNODES - 1) >> BSHIFT;   // 391 buckets

    char* w = (char*)d_ws;
    size_t off = 0;
    auto alloc = [&](size_t bytes) -> char* {
        char* p = w + off;
        off = (off + bytes + 255) & ~(size_t)255;
        return p;
    };
    int*      bucket_cnt    = (int*)alloc((size_t)NB * 4);
    int*      bucket_base   = (int*)alloc((size_t)(NB + 1) * 4);
    int*      bucket_cursor = (int*)alloc((size_t)NB * 4);
    unsigned* bucketed      = (unsigned*)alloc((size_t)E * 4);
    int*      rowstart      = (int*)alloc((size_t)(N + 1) * 4);
    float*    dinv          = (float*)alloc((size_t)N * 4);
    int*      csr           = (int*)alloc((size_t)E * 4);
    _Float16* wt1           = (_Float16*)alloc((size_t)128 * 128 * 2);
    _Float16* wt2           = (_Float16*)alloc((size_t)256 * 128 * 2);
    _Float16* xs            = (_Float16*)alloc((size_t)N * 128 * 2);
    _Float16* q1            = (_Float16*)alloc((size_t)N * 128 * 2);
    _Float16* p2            = (_Float16*)alloc((size_t)N * 128 * 2);
    _Float16* q2            = (_Float16*)alloc((size_t)N * 128 * 2);

    int chunk = (E + 255) / 256;          // edges per Phase-A block
    size_t lds1 = (size_t)NB * 4;         // count hist
    size_t lds3 = (size_t)NB * 12;        // scatter hist+base+cur

    hipMemsetAsync(bucket_cnt, 0, (size_t)NB * 4, stream);
    hipLaunchKernelGGL(count_conv_kernel, dim3(256 + 192), dim3(256), lds1, stream,
                       dst, bucket_cnt, W1, W2, wt1, wt2, E, chunk, NB);
    hipLaunchKernelGGL(bucket_scan_kernel, dim3(1), dim3(512), 0, stream, bucket_cnt, bucket_base, bucket_cursor, NB);
    hipLaunchKernelGGL(bucket_scatter_kernel, dim3(256), dim3(256), lds3, stream, src, dst, bucket_cursor, bucketed, E, chunk, NB);
    hipLaunchKernelGGL(build_kernel, dim3(NB), dim3(256), 0, stream, bucketed, bucket_base, x, rowstart, dinv, csr, xs, N, E, NB);

    int gbm = (N + 127) / 128;
    int nb_agg = (N + 3) / 4;
    // layer 1
    hipLaunchKernelGGL(agg128_kernel, dim3(nb_agg), dim3(256), 0, stream, xs, rowstart, csr, dinv, q1, N);
    hipLaunchKernelGGL((gemm_kernel<true>), dim3(gbm, 1), dim3(256), 0, stream, q1, wt1, b1, dinv, (void*)p2, N, 128);
    // layer 2
    hipLaunchKernelGGL(agg128_kernel, dim3(nb_agg), dim3(256), 0, stream, p2, rowstart, csr, dinv, q2, N);
    hipLaunchKernelGGL((gemm_kernel<false>), dim3(gbm, 2), dim3(256), 0, stream, q2, wt2, b2, dinv, (void*)out, N, 256);
}